// Round 5
// baseline (321.908 us; speedup 1.0000x reference)
//
#include <hip/hip_runtime.h>

// PETP_Quadratic: y = sum_t fctp(x_t, x_t, W_t), t in {self, flavor, nunubar, all}
// Pair-feature GEMM, fp16 MFMA 32x32x16, fp32 accumulate.
//   y_s[p,w]   = [s s^T].norm*W0  +  [Gram(v)].norm*inv_sqrt3*W1
//   y_v[p,w,k] = [s[u] v[v,k]].norm*(W2[u,v,w] + W3[v,u,w])
// R5: one 32-pos tile/wave => 1 position/lane => broadcast features in registers,
// k-loops fully unrolled => compile-time extracts, zero LDS in the inner loop.

typedef _Float16 half8 __attribute__((ext_vector_type(8)));
typedef float  floatx16 __attribute__((ext_vector_type(16)));

#define NORM 0.022097086912079608f   /* 1/(32*sqrt(2)) */
#define INV_SQRT3 0.5773502691896258f
#define FR 136   /* feat row stride (halfwords); 272 B = multiple of 16 B */

__global__ void prep_kernel(const float* __restrict__ Wa, const float* __restrict__ Wb,
                            const float* __restrict__ Wc, const float* __restrict__ Wd,
                            _Float16* __restrict__ B1s, _Float16* __restrict__ B2s) {
    const float* Ws[4] = {Wa, Wb, Wc, Wd};
    int idx = blockIdx.x * 256 + threadIdx.x;
    if (idx < 262144) {
        int j    = idx & 7;
        int lane = (idx >> 3) & 63;
        int f    = (idx >> 9) & 127;
        int t    = idx >> 16;
        int n = lane & 31;
        int k = f * 16 + (lane >> 5) * 8 + j;
        int seg = k >> 10, u = (k >> 5) & 31, v = k & 31;
        const float* W = Ws[t];
        float val;
        if (seg == 0) val = NORM * W[0 * 32768 + u * 1024 + v * 32 + n];
        else          val = NORM * INV_SQRT3 * W[1 * 32768 + u * 1024 + v * 32 + n];
        B1s[idx] = (_Float16)val;
    } else {
        int idx2 = idx - 262144;
        if (idx2 < 131072) {
            int j    = idx2 & 7;
            int lane = (idx2 >> 3) & 63;
            int f    = (idx2 >> 9) & 63;
            int t    = idx2 >> 15;
            int n = lane & 31;
            int k = f * 16 + (lane >> 5) * 8 + j;
            int u = k >> 5, v = k & 31;
            const float* W = Ws[t];
            float val = NORM * (W[2 * 32768 + u * 1024 + v * 32 + n] +
                                W[3 * 32768 + v * 1024 + u * 32 + n]);
            B2s[idx2] = (_Float16)val;
        }
    }
}

__launch_bounds__(192, 2)
__global__ void petp_main(const float* __restrict__ x,
                          const _Float16* __restrict__ B1s,
                          const _Float16* __restrict__ B2s,
                          float* __restrict__ y) {
    __shared__ _Float16 feat[96 * FR];   // 26112 B

    const int tid  = threadIdx.x;
    const int wave = tid / 64;
    const int lane = tid & 63;
    const int n32 = lane & 31;
    const int q2  = lane >> 5;
    const int wg = blockIdx.x;
    const int pbase = wave * 32;
    const int pos = pbase + n32;

    floatx16 acc_s = {0.f};
    floatx16 acc_v[3];
#pragma unroll
    for (int i = 0; i < 3; ++i) acc_v[i] = acc_s;

    const float* xg = x + (size_t)wg * (96 * 128);

#pragma unroll 1
    for (int t = 0; t < 4; ++t) {
        __syncthreads();
#pragma unroll 1
        for (int it = 0; it < 11; ++it) {
            int item = it * 192 + tid;
            if (item < 2048) {
                int b = item >> 7;
                int c = item & 127;
                const float* bp = xg + b * 768 + c;
                float v00 = bp[0],   v01 = bp[128], v02 = bp[256];
                float v10 = bp[384], v11 = bp[512], v12 = bp[640];
                float rs0 = v00 + v01 + v02, rs1 = v10 + v11 + v12;
                float cs0 = v00 + v10, cs1 = v01 + v11, cs2 = v02 + v12;
                float tot = rs0 + rs1;
                float xv[6] = {v00, v01, v02, v10, v11, v12};
                float rs[2] = {rs0, rs1};
                float cs[3] = {cs0, cs1, cs2};
                int col;
                if (c < 32) col = c;
                else { int cc = c - 32; col = 32 + (cc % 3) * 32 + (cc / 3); }
#pragma unroll
                for (int p6 = 0; p6 < 6; ++p6) {
                    int i = p6 / 3, j = p6 % 3;
                    float xvv = xv[p6];
                    float f;
                    if      (t == 0) f = xvv;
                    else if (t == 1) f = (rs[i] - xvv) * 0.5f;
                    else if (t == 2) f = cs[j] - xvv;
                    else             f = (tot - rs[i] - cs[j] + xvv) * 0.5f;
                    int posL = b * 6 + p6;
                    feat[posL * FR + col] = (_Float16)f;
                }
            }
        }
        __syncthreads();

        const _Float16* fr = &feat[pos * FR];
        half8 s_all[4];
        half8 v_all[3][4];
#pragma unroll
        for (int j4 = 0; j4 < 4; ++j4) s_all[j4] = *(const half8*)(fr + j4 * 8);
#pragma unroll
        for (int i = 0; i < 3; ++i)
#pragma unroll
            for (int j4 = 0; j4 < 4; ++j4)
                v_all[i][j4] = *(const half8*)(fr + 32 + i * 32 + j4 * 8);
        half8 p_ss[2];
        half8 p_v[3][2];
#pragma unroll
        for (int h = 0; h < 2; ++h) {
            p_ss[h] = *(const half8*)(fr + h * 16 + q2 * 8);
#pragma unroll
            for (int i = 0; i < 3; ++i)
                p_v[i][h] = *(const half8*)(fr + 32 + i * 32 + h * 16 + q2 * 8);
        }

        const _Float16* B1v = B1s + t * 65536 + lane * 8;
        const _Float16* B2v = B2s + t * 32768 + lane * 8;

#pragma unroll
        for (int ku = 0; ku < 32; ++ku) {
            half8 c1a = *(const half8*)(B1v + (2 * ku + 0) * 512);
            half8 c1b = *(const half8*)(B1v + (2 * ku + 1) * 512);
            half8 c2a = *(const half8*)(B2v + (2 * ku + 0) * 512);
            half8 c2b = *(const half8*)(B2v + (2 * ku + 1) * 512);
            _Float16 bc = s_all[ku >> 3][ku & 7];
            acc_s = __builtin_amdgcn_mfma_f32_32x32x16_f16(p_ss[0] * bc, c1a, acc_s, 0, 0, 0);
            acc_s = __builtin_amdgcn_mfma_f32_32x32x16_f16(p_ss[1] * bc, c1b, acc_s, 0, 0, 0);
#pragma unroll
            for (int kc = 0; kc < 3; ++kc) {
                acc_v[kc] = __builtin_amdgcn_mfma_f32_32x32x16_f16(p_v[kc][0] * bc, c2a, acc_v[kc], 0, 0, 0);
                acc_v[kc] = __builtin_amdgcn_mfma_f32_32x32x16_f16(p_v[kc][1] * bc, c2b, acc_v[kc], 0, 0, 0);
            }
        }
#pragma unroll
        for (int ku = 0; ku < 32; ++ku) {
            half8 g1a = *(const half8*)(B1v + (64 + 2 * ku + 0) * 512);
            half8 g1b = *(const half8*)(B1v + (64 + 2 * ku + 1) * 512);
            _Float16 b0 = v_all[0][ku >> 3][ku & 7];
            _Float16 b1 = v_all[1][ku >> 3][ku & 7];
            _Float16 b2 = v_all[2][ku >> 3][ku & 7];
            half8 af0 = p_v[0][0] * b0 + p_v[1][0] * b1 + p_v[2][0] * b2;
            half8 af1 = p_v[0][1] * b0 + p_v[1][1] * b1 + p_v[2][1] * b2;
            acc_s = __builtin_amdgcn_mfma_f32_32x32x16_f16(af0, g1a, acc_s, 0, 0, 0);
            acc_s = __builtin_amdgcn_mfma_f32_32x32x16_f16(af1, g1b, acc_s, 0, 0, 0);
        }
    }

    float* yg = y + (size_t)wg * (96 * 128);
    const int w = n32;
#pragma unroll
    for (int r = 0; r < 16; ++r) {
        int row = (r & 3) + 8 * (r >> 2) + 4 * q2;
        int p = pbase + row;
        yg[p * 128 + w] = acc_s[r];
#pragma unroll
        for (int kc = 0; kc < 3; ++kc)
            yg[p * 128 + 32 + 3 * w + kc] = acc_v[kc][r];
    }
}

extern "C" void kernel_launch(void* const* d_in, const int* in_sizes, int n_in,
                              void* d_out, int out_size, void* d_ws, size_t ws_size,
                              hipStream_t stream) {
    const float* x  = (const float*)d_in[0];
    const float* Wa = (const float*)d_in[1];
    const float* Wb = (const float*)d_in[2];
    const float* Wc = (const float*)d_in[3];
    const float* Wd = (const float*)d_in[4];
    float* y = (float*)d_out;

    _Float16* B1s = (_Float16*)d_ws;           // 262144 half = 512 KB
    _Float16* B2s = B1s + 262144;              // 131072 half = 256 KB

    int nbatch = in_sizes[0] / 768;            // 16384
    int nwg = nbatch / 16;                     // 1024

    prep_kernel<<<(262144 + 131072) / 256, 256, 0, stream>>>(Wa, Wb, Wc, Wd, B1s, B2s);
    petp_main<<<nwg, 192, 0, stream>>>(x, B1s, B2s, y);
}